// Round 6
// baseline (437.742 us; speedup 1.0000x reference)
//
#include <hip/hip_runtime.h>

// PSP: syn_t = 0.5*(syn_{t-1} + x_t), tau=2. Shapes (T=64, N=512, C=2048) f32.
// Chunked-scan decomposition: 4 chunks of 16 timesteps, one wave per chunk,
// 64 float4-columns per block. LDS exchange of chunk-final states gives the
// carry (weights 2^-16, 2^-32 are exact).
//
// Round-5 lesson: kernel ran ~167us (~3.1 TB/s) — 2x off the copy ceiling.
// Suspected cause: the scan consumes v[j] in order, so the scheduler sinks
// load j to just before its use, collapsing the 16-wide load batch (same
// collapse as round 2, where VGPR=36 proved it). Fix: empty asm with "+v"
// constraints on all 16 registers pins the whole batch live before the scan.

typedef float f4 __attribute__((ext_vector_type(4)));

#define NC4 (512 * 2048 / 4)   // 262144 float4 columns per timestep
#define CHUNK 16
#define NCHUNK 4               // T / CHUNK
#define COLS 64                // float4-columns per block (one wave per chunk)

__global__ __launch_bounds__(256) void psp_scan_kernel(
    const f4* __restrict__ in, f4* __restrict__ out) {
    const int col   = threadIdx.x & (COLS - 1);
    const int chunk = threadIdx.x >> 6;              // wave id == chunk id
    const int colIdx = blockIdx.x * COLS + col;      // [0, NC4)

    const f4* ip = in  + (size_t)(chunk * CHUNK) * NC4 + colIdx;
    f4*       op = out + (size_t)(chunk * CHUNK) * NC4 + colIdx;

    // 1) 16 independent loads — forced to ALL be in flight before any use
    f4 v[CHUNK];
#pragma unroll
    for (int j = 0; j < CHUNK; ++j)
        v[j] = ip[(size_t)j * NC4];

    // Scheduling fence: forces every v[j] materialized here, so the compiler
    // cannot sink individual loads into the scan chain below.
    asm volatile(""
        : "+v"(v[0]),  "+v"(v[1]),  "+v"(v[2]),  "+v"(v[3]),
          "+v"(v[4]),  "+v"(v[5]),  "+v"(v[6]),  "+v"(v[7]),
          "+v"(v[8]),  "+v"(v[9]),  "+v"(v[10]), "+v"(v[11]),
          "+v"(v[12]), "+v"(v[13]), "+v"(v[14]), "+v"(v[15]));

    // 2) local scan (serial 16-FMA chain, in registers)
    f4 acc = {0.f, 0.f, 0.f, 0.f};
#pragma unroll
    for (int j = 0; j < CHUNK; ++j) {
        acc = 0.5f * (acc + v[j]);
        v[j] = acc;
    }

    // 3) exchange chunk-final states (4 KB LDS)
    __shared__ f4 finals[NCHUNK][COLS];
    finals[chunk][col] = acc;
    __syncthreads();

    f4 carry = {0.f, 0.f, 0.f, 0.f};
    if (chunk >= 1) carry = finals[chunk - 1][col];
    if (chunk >= 2) carry += finals[chunk - 2][col] * 0x1p-16f;
    if (chunk >= 3) carry += finals[chunk - 3][col] * 0x1p-32f;

    // 4) fixup + store: global_j = local_j + carry * 0.5^{j+1}
    float d = 0.5f;
#pragma unroll
    for (int j = 0; j < CHUNK; ++j) {
        op[(size_t)j * NC4] = v[j] + carry * d;
        d *= 0.5f;
    }
}

extern "C" void kernel_launch(void* const* d_in, const int* in_sizes, int n_in,
                              void* d_out, int out_size, void* d_ws, size_t ws_size,
                              hipStream_t stream) {
    const f4* in = (const f4*)d_in[0];
    f4* out = (f4*)d_out;
    // 262144 columns / 64 per block = 4096 blocks of 256 threads (exact fit)
    psp_scan_kernel<<<NC4 / COLS, 256, 0, stream>>>(in, out);
}